// Round 4
// baseline (305.031 us; speedup 1.0000x reference)
//
#include <hip/hip_runtime.h>
#include <math.h>

#define O_  32
#define I_  32
#define K_  13
#define N_  4096
#define IK  (I_ * K_)     // 416
#define OIK (O_ * IK)     // 13312
#define NB  4             // n's per block in stream kernel

typedef float f32x4 __attribute__((ext_vector_type(4)));

// Kernel 1: materialize g[n][i][k] = x[i*N + shifts[n*13+k]] into d_ws.
// Pure elementwise gather: no barriers, scattered x reads are L2-hot
// (x = 512 KB), writes fully coalesced. N*IK = 1,703,936 = 6656 * 256.
__global__ __launch_bounds__(256) void gather_kernel(
    const float* __restrict__ x,      // (I, N)
    const int*   __restrict__ shifts, // (N, K)
    float* __restrict__ g)            // (N, I, K) in ws
{
    int idx = blockIdx.x * 256 + threadIdx.x;
    int n = idx / IK;
    int r = idx - n * IK;
    int i = r / K_;
    int k = r - i * K_;
    int s = shifts[n * K_ + k];
    g[idx] = x[i * N_ + s];
}

// Kernel 2: pure stream, no LDS, no __syncthreads.
// 8 threads per o; W fragment (13 float4) hoisted into registers for the
// whole block; mask streamed nontemporally; 4 split accumulators.
__global__ __launch_bounds__(256, 2) void stream_kernel(
    const float* __restrict__ g,      // (N, I, K)
    const float* __restrict__ W,      // (O, I, K)
    const float* __restrict__ b,      // (O,)
    const float* __restrict__ mask,   // (N, O, I, K)
    float* __restrict__ out)          // (O, N)
{
    const int n0  = blockIdx.x * NB;
    const int tid = threadIdx.x;
    const int o   = tid >> 3;
    const int s8  = tid & 7;

    const f32x4* w4 = (const f32x4*)(W + o * IK);
    f32x4 w[13];
#pragma unroll
    for (int m = 0; m < 13; ++m) w[m] = w4[s8 + 8 * m];

    const float scale = (float)((2.0 + 2.0 * M_E) / (M_E - 1.0));
    const float bo = b[o];

    for (int nl = 0; nl < NB; ++nl) {
        const int n = n0 + nl;
        const f32x4* g4 = (const f32x4*)(g + (size_t)n * IK);
        const f32x4* m4 = (const f32x4*)(mask + (size_t)n * OIK + o * IK);

        // wg = W * g (g reads are 128B-broadcast across the 8 o-groups, L2-hot)
        f32x4 wg[13];
#pragma unroll
        for (int m = 0; m < 13; ++m) wg[m] = w[m] * g4[s8 + 8 * m];

        // Hot loop: nontemporal mask load + 4 FMAs, split accumulators.
        float a0 = 0.f, a1 = 0.f, a2 = 0.f, a3 = 0.f;
#pragma unroll
        for (int m = 0; m < 13; ++m) {
            f32x4 mv = __builtin_nontemporal_load(&m4[s8 + 8 * m]);
            a0 = fmaf(mv.x, wg[m].x, a0);
            a1 = fmaf(mv.y, wg[m].y, a1);
            a2 = fmaf(mv.z, wg[m].z, a2);
            a3 = fmaf(mv.w, wg[m].w, a3);
        }
        float acc = (a0 + a1) + (a2 + a3);

        acc += __shfl_down(acc, 4);
        acc += __shfl_down(acc, 2);
        acc += __shfl_down(acc, 1);

        if (s8 == 0) {
            float y  = acc + bo;
            float sg = 1.0f / (1.0f + __expf(-y));
            out[o * N_ + n] = (sg - 0.5f) * scale;
        }
    }
}

extern "C" void kernel_launch(void* const* d_in, const int* in_sizes, int n_in,
                              void* d_out, int out_size, void* d_ws, size_t ws_size,
                              hipStream_t stream) {
    const float* x      = (const float*)d_in[0];
    const float* Wconv  = (const float*)d_in[1];
    const float* bconv  = (const float*)d_in[2];
    const float* mask   = (const float*)d_in[3];
    const int*   shifts = (const int*)d_in[4];
    float* out = (float*)d_out;
    float* g   = (float*)d_ws;   // 6.8 MB of the workspace

    gather_kernel<<<(N_ * IK) / 256, 256, 0, stream>>>(x, shifts, g);
    stream_kernel<<<N_ / NB, 256, 0, stream>>>(g, Wconv, bconv, mask, out);
}

// Round 5
// 290.380 us; speedup vs baseline: 1.0505x; 1.0505x over previous
//
#include <hip/hip_runtime.h>
#include <math.h>

#define O_  32
#define I_  32
#define K_  13
#define N_  4096
#define IK  (I_ * K_)     // 416
#define OIK (O_ * IK)     // 13312
#define NB  4             // n's per block

typedef float f32x4 __attribute__((ext_vector_type(4)));

// Single kernel: one LDS gather + one barrier per NB n's, then a pure
// nontemporal mask stream with W held in registers for the whole block.
__global__ __launch_bounds__(256) void plaq_kernel(
    const float* __restrict__ x,      // (I, N)
    const float* __restrict__ W,      // (O, I, K)
    const float* __restrict__ b,      // (O,)
    const float* __restrict__ mask,   // (N, O, I, K)
    const int*   __restrict__ shifts, // (N, K)
    float* __restrict__ out)          // (O, N)
{
    __shared__ __align__(16) float g_lds[NB][IK];
    const int n0  = blockIdx.x * NB;
    const int tid = threadIdx.x;

    // Gather g[nl][i*13+k] = x[i*N + shifts[(n0+nl)*13+k]]  (1664 elems).
    for (int idx = tid; idx < NB * IK; idx += 256) {
        int nl = idx / IK;
        int r  = idx - nl * IK;
        int i  = r / K_;
        int k  = r - i * K_;
        int s  = shifts[(n0 + nl) * K_ + k];
        g_lds[nl][r] = x[i * N_ + s];
    }

    // Hoist W into registers while the gather is in flight (independent).
    const int o  = tid >> 3;
    const int s8 = tid & 7;
    const f32x4* w4 = (const f32x4*)(W + o * IK);
    f32x4 w[13];
#pragma unroll
    for (int m = 0; m < 13; ++m) w[m] = w4[s8 + 8 * m];
    const float bo = b[o];

    __syncthreads();

    const float scale = (float)((2.0 + 2.0 * M_E) / (M_E - 1.0));

    for (int nl = 0; nl < NB; ++nl) {
        const int n = n0 + nl;
        const f32x4* m4 = (const f32x4*)(mask + (size_t)n * OIK + o * IK);
        const f32x4* g4 = (const f32x4*)(&g_lds[nl][0]);

        // wg = W * g  (g from LDS, broadcast across the 8 o-groups).
        f32x4 wg[13];
#pragma unroll
        for (int m = 0; m < 13; ++m) wg[m] = w[m] * g4[s8 + 8 * m];

        // Hot loop: one nontemporal 16B mask load + 4 FMAs per iteration.
        float a0 = 0.f, a1 = 0.f, a2 = 0.f, a3 = 0.f;
#pragma unroll
        for (int m = 0; m < 13; ++m) {
            f32x4 mv = __builtin_nontemporal_load(&m4[s8 + 8 * m]);
            a0 = fmaf(mv.x, wg[m].x, a0);
            a1 = fmaf(mv.y, wg[m].y, a1);
            a2 = fmaf(mv.z, wg[m].z, a2);
            a3 = fmaf(mv.w, wg[m].w, a3);
        }
        float acc = (a0 + a1) + (a2 + a3);

        // Reduce across the 8 lanes sharing this o (within one wave).
        acc += __shfl_down(acc, 4);
        acc += __shfl_down(acc, 2);
        acc += __shfl_down(acc, 1);

        if (s8 == 0) {
            float y  = acc + bo;
            float sg = 1.0f / (1.0f + __expf(-y));
            out[o * N_ + n] = (sg - 0.5f) * scale;
        }
    }
}

extern "C" void kernel_launch(void* const* d_in, const int* in_sizes, int n_in,
                              void* d_out, int out_size, void* d_ws, size_t ws_size,
                              hipStream_t stream) {
    const float* x      = (const float*)d_in[0];
    const float* Wconv  = (const float*)d_in[1];
    const float* bconv  = (const float*)d_in[2];
    const float* mask   = (const float*)d_in[3];
    const int*   shifts = (const int*)d_in[4];
    float* out = (float*)d_out;

    plaq_kernel<<<N_ / NB, 256, 0, stream>>>(x, Wconv, bconv, mask, shifts, out);
}